// Round 14
// baseline (57.032 us; speedup 1.0000x reference)
//
#include <hip/hip_runtime.h>

#define BB    4
#define NN    8192
#define KK    16
#define CIN   64
#define COUTC 64
#define P     16           // points per block (= MFMA M-tile)

typedef short bf16x8 __attribute__((ext_vector_type(8)));
typedef float f32x4  __attribute__((ext_vector_type(4)));
typedef float f32x2  __attribute__((ext_vector_type(2)));
typedef unsigned short u16x4 __attribute__((ext_vector_type(4)));

__device__ __forceinline__ unsigned short f2bf_rne(float f) {
    unsigned int u = __builtin_bit_cast(unsigned int, f);
    u += 0x7fffu + ((u >> 16) & 1u);
    return (unsigned short)(u >> 16);
}

__device__ __forceinline__ unsigned int pack_bf2(float lo, float hi) {
    return (unsigned int)f2bf_rne(lo) | ((unsigned int)f2bf_rne(hi) << 16);
}

// ---- fused prep: [0,8192) inp->bf16 tile-transposed ; [8192,8448) Wt ; 8448 fold ----
// inp_bf[n*64 + r*4 + t4] = inp[n*64 + t4*16 + r]  (r=cin%16, t4=cin/16)
__global__ __launch_bounds__(256) void prep_all(
    const float* __restrict__ inp, unsigned short* __restrict__ inp_bf,
    const float* __restrict__ W, unsigned short* __restrict__ Wt,
    const float* __restrict__ l1w, const float* __restrict__ l1b,
    const float* __restrict__ centers, float* __restrict__ A1)
{
    const int blk = blockIdx.x;
    const int t   = threadIdx.x;
    if (blk < 8192) {
        const int o  = blk * 256 + t;                  // 2M total
        const int n  = o >> 6;
        const int q  = o & 63;
        const int r  = q >> 2;
        const int t4 = q & 3;
        inp_bf[o] = f2bf_rne(inp[n * 64 + t4 * 16 + r]);
    } else if (blk < 8448) {
        const int o    = (blk - 8192) * 256 + t;       // 65536 total
        const int cout = o >> 10;
        const int kp   = o & 1023;
        const int m    = kp >> 6;
        const int cin  = kp & 63;
        Wt[o] = f2bf_rne(W[(cin * 16 + m) * 64 + cout] * (1.0f / 16.0f));
    } else if (t < 32) {
        float bb = l1b[t];
        float a0 = 0.f, a1 = 0.f, a2 = 0.f;
        for (int c = 0; c < 16; ++c) {
            const float w0 = l1w[(c     ) * 32 + t];
            const float w1 = l1w[(16 + c) * 32 + t];
            const float w2 = l1w[(32 + c) * 32 + t];
            a0 += w0; a1 += w1; a2 += w2;
            bb -= centers[c] * w0 + centers[16 + c] * w1 + centers[32 + c] * w2;
        }
        A1[0 * 32 + t] = a0; A1[1 * 32 + t] = a1; A1[2 * 32 + t] = a2; A1[3 * 32 + t] = bb;
    }
}

__global__ __launch_bounds__(256, 2) void ptconv_fused(
    const unsigned short* __restrict__ inp_bf, // [B,N,16,4] bf16 tile-transposed (prep)
    const float* __restrict__ points,    // [B,N,3]
    const float* __restrict__ next_pts,  // [B,N,3]
    const int*   __restrict__ indices,   // [B,N,K]
    const unsigned short* __restrict__ Wt, // [COUT][1024] bf16 (prep)
    const float* __restrict__ A1f,       // [4][32] folded layer-1 (prep, SoA)
    const float* __restrict__ bias,      // [COUT]
    const float* __restrict__ l2w, const float* __restrict__ l2b,  // [32,16],[16]
    const float* __restrict__ l3w, const float* __restrict__ l3b,  // [16,16],[16]
    float* __restrict__ out)             // [B,N,COUT]
{
    const int t    = threadIdx.x;
    const int lane = t & 63;
    const int w    = t >> 6;             // wave id 0..3
    const int pt0  = blockIdx.x * P;
    const int b    = pt0 >> 13;          // pt0 / NN

    // ONE shared array, 16 KB: per point p a 1024-B window.
    //  - phase 1 writes h3t[p] (512 B, layout m*32+k*2, XOR (p&3)<<5) into the window;
    //  - phase 2 reads h3t[p] (same wave) THEN overwrites the window with f[p]'s
    //    even-cin half (1024 B, XOR ((p&7)^(arow&7))<<4). Same array => compiler keeps
    //    ds op order (may-alias); same wave => HW in-order. (round-5 lesson applied)
    __shared__ unsigned short s_u[P][512];        // 16 KB -> 8+ blocks/CU (all work resident)

    const f32x2 zero2 = {0.f, 0.f};

    // ---------------- phase 1: MLP packed f32, weights via scalar loads ----------------
    {
        const int p = t >> 4, k = t & 15;
        const int pt = pt0 + p;
        const int id = indices[(size_t)pt0 * KK + t];  // coalesced
        const float* pp = points + ((size_t)(b * NN + id)) * 3;
        const float* np = next_pts + (size_t)pt * 3;
        const float px = pp[0] - np[0];
        const float py = pp[1] - np[1];
        const float pz = pp[2] - np[2];
        const f32x2 px2 = {px, px}, py2 = {py, py}, pz2 = {pz, pz};

        const f32x2* A0  = (const f32x2*)(A1f);
        const f32x2* A1v = (const f32x2*)(A1f + 32);
        const f32x2* A2  = (const f32x2*)(A1f + 64);
        const f32x2* A3  = (const f32x2*)(A1f + 96);
        f32x2 h1[16];
        #pragma unroll
        for (int j = 0; j < 16; ++j) {
            f32x2 a = __builtin_elementwise_fma(pz2, A2[j], A3[j]);
            a = __builtin_elementwise_fma(py2, A1v[j], a);
            a = __builtin_elementwise_fma(px2, A0[j], a);
            h1[j] = __builtin_elementwise_max(a, zero2);
        }

        f32x2 h2[8];
        {
            const f32x2* b2p = (const f32x2*)l2b;
            #pragma unroll
            for (int j = 0; j < 8; ++j) h2[j] = b2p[j];
        }
        #pragma unroll
        for (int i = 0; i < 32; ++i) {
            const float hv = h1[i >> 1][i & 1];
            const f32x2 hvv = {hv, hv};
            const f32x2* wr = (const f32x2*)(l2w + i * 16);   // uniform -> s_load
            #pragma unroll
            for (int j = 0; j < 8; ++j)
                h2[j] = __builtin_elementwise_fma(hvv, wr[j], h2[j]);
        }
        #pragma unroll
        for (int j = 0; j < 8; ++j) h2[j] = __builtin_elementwise_max(h2[j], zero2);

        f32x2 h3v[8];
        {
            const f32x2* b3p = (const f32x2*)l3b;
            #pragma unroll
            for (int j = 0; j < 8; ++j) h3v[j] = b3p[j];
        }
        #pragma unroll
        for (int i = 0; i < 16; ++i) {
            const float hv = h2[i >> 1][i & 1];
            const f32x2 hvv = {hv, hv};
            const f32x2* wr = (const f32x2*)(l3w + i * 16);   // uniform -> s_load
            #pragma unroll
            for (int j = 0; j < 8; ++j)
                h3v[j] = __builtin_elementwise_fma(hvv, wr[j], h3v[j]);
        }
        char* ub = (char*)s_u;
        const unsigned int hsw = ((unsigned)(p & 3)) << 5;
        #pragma unroll
        for (int j = 0; j < 8; ++j) {
            const f32x2 v = __builtin_elementwise_max(h3v[j], zero2);
            const unsigned int b0 = ((unsigned)(p * 1024 + (2 * j    ) * 32 + k * 2)) ^ hsw;
            const unsigned int b1 = ((unsigned)(p * 1024 + (2 * j + 1) * 32 + k * 2)) ^ hsw;
            *(unsigned short*)(ub + b0) = f2bf_rne(v[0]);
            *(unsigned short*)(ub + b1) = f2bf_rne(v[1]);
        }
    }
    // phase 2 of wave w reads ONLY point-windows w*4..w*4+3, written by this same wave.
    __threadfence_block();

    // ---------------- phase 2: f = feats @ h3 via MFMA; tiles 0,1 -> LDS (overlay), 2,3 -> regs ----------------
    uint2 holdA[2][2], holdB[2][2];          // [pr][tile-2], static-indexed (unrolled)
    {
        const int arow = lane & 15;          // A-row = cin_local ; B-col = m
        const int hi   = lane >> 4;
        const int kg   = (hi & 1) * 8;       // k-group base within the 16 real k
        const unsigned short* ibase = inp_bf + (size_t)b * NN * 64;
        const int* idxg = indices + (size_t)pt0 * KK;
        const bf16x8 vzero = {0, 0, 0, 0, 0, 0, 0, 0};
        char* fbb = (char*)s_u;

        #pragma unroll
        for (int pr = 0; pr < 2; ++pr) {
            const int pA  = w * 4 + pr * 2;
            const int pB  = pA + 1;
            const int myp = (hi < 2) ? pA : pB;

            const int4 i0 = *(const int4*)&idxg[myp * 16 + kg];
            const int4 i1 = *(const int4*)&idxg[myp * 16 + kg + 4];
            const int ids[8] = {i0.x, i0.y, i0.z, i0.w, i1.x, i1.y, i1.z, i1.w};

            // one 8B load per neighbor row: elements {cin = t4*16 + arow, t4=0..3}
            u16x4 rows[8];
            #pragma unroll
            for (int jj = 0; jj < 8; ++jj)
                rows[jj] = *(const u16x4*)(ibase + (size_t)ids[jj] * 64 + arow * 4);

            // read h3t BEFORE overwriting this window with f
            const unsigned int hb = ((unsigned)(myp * 1024 + arow * 32 + kg * 2))
                                    ^ (((unsigned)(myp & 3)) << 5);
            const bf16x8 vfull = *(const bf16x8*)((const char*)s_u + hb);
            const bf16x8 bfA = (hi < 2) ? vfull : vzero;
            const bf16x8 bfB = (hi < 2) ? vzero : vfull;

            #pragma unroll
            for (int tile = 0; tile < 4; ++tile) {
                bf16x8 af;
                #pragma unroll
                for (int jj = 0; jj < 8; ++jj) af[jj] = (short)rows[jj][tile];
                const f32x4 z4 = {0.f, 0.f, 0.f, 0.f};
                const f32x4 dA = __builtin_amdgcn_mfma_f32_16x16x32_bf16(af, bfA, z4, 0, 0, 0);
                const f32x4 dB = __builtin_amdgcn_mfma_f32_16x16x32_bf16(af, bfB, z4, 0, 0, 0);
                const uint2 vA = make_uint2(pack_bf2(dA[0], dA[1]), pack_bf2(dA[2], dA[3]));
                const uint2 vB = make_uint2(pack_bf2(dB[0], dB[1]), pack_bf2(dB[2], dB[3]));
                if (tile < 2) {
                    // even half: cin' = tile*16 + hi*4 + r  in [0,32)
                    const unsigned int baseo = (unsigned)(arow * 64 + tile * 32 + hi * 8);
                    const unsigned int offA = ((unsigned)(pA * 1024) + baseo)
                                              ^ (((unsigned)((pA & 7) ^ (arow & 7))) << 4);
                    const unsigned int offB = ((unsigned)(pB * 1024) + baseo)
                                              ^ (((unsigned)((pB & 7) ^ (arow & 7))) << 4);
                    *(uint2*)(fbb + offA) = vA;
                    *(uint2*)(fbb + offB) = vB;
                } else {
                    holdA[pr][tile - 2] = vA;
                    holdB[pr][tile - 2] = vB;
                }
            }
        }
    }
    __syncthreads();

    // ---------------- phase 3: even k-pass, swap halves, odd k-pass ----------------
    {
        const int arow = lane & 15;      // A row = point ; B col = cout_local
        const int hi   = lane >> 4;
        const unsigned short* wb = Wt + (size_t)(w * 16 + arow) * 1024 + hi * 8;
        const char* fbb = (const char*)s_u;
        f32x4 acc = {0.f, 0.f, 0.f, 0.f};

        #pragma unroll
        for (int m = 0; m < 16; ++m) {   // even kk = 2m  (cin 0..31)
            const unsigned int xr = ((unsigned)((arow & 7) ^ (m & 7))) << 4;
            const bf16x8 av = *(const bf16x8*)(fbb +
                (((unsigned)(arow * 1024 + m * 64 + hi * 16)) ^ xr));
            const bf16x8 bv = *(const bf16x8*)(wb + m * 64);
            acc = __builtin_amdgcn_mfma_f32_16x16x32_bf16(av, bv, acc, 0, 0, 0);
        }
        __syncthreads();                 // even half fully read

        {   // write odd half (cin 32..63) from hold regs
            char* fbw = (char*)s_u;
            #pragma unroll
            for (int pr = 0; pr < 2; ++pr) {
                const int pA = w * 4 + pr * 2;
                const int pB = pA + 1;
                #pragma unroll
                for (int t2 = 0; t2 < 2; ++t2) {
                    const unsigned int baseo = (unsigned)(arow * 64 + t2 * 32 + hi * 8);
                    const unsigned int offA = ((unsigned)(pA * 1024) + baseo)
                                              ^ (((unsigned)((pA & 7) ^ (arow & 7))) << 4);
                    const unsigned int offB = ((unsigned)(pB * 1024) + baseo)
                                              ^ (((unsigned)((pB & 7) ^ (arow & 7))) << 4);
                    *(uint2*)(fbw + offA) = holdA[pr][t2];
                    *(uint2*)(fbw + offB) = holdB[pr][t2];
                }
            }
        }
        __syncthreads();                 // odd half visible

        #pragma unroll
        for (int m = 0; m < 16; ++m) {   // odd kk = 2m+1  (cin 32..63)
            const unsigned int xr = ((unsigned)((arow & 7) ^ (m & 7))) << 4;
            const bf16x8 av = *(const bf16x8*)(fbb +
                (((unsigned)(arow * 1024 + m * 64 + hi * 16)) ^ xr));
            const bf16x8 bv = *(const bf16x8*)(wb + m * 64 + 32);
            acc = __builtin_amdgcn_mfma_f32_16x16x32_bf16(av, bv, acc, 0, 0, 0);
        }

        const float bvs = bias[w * 16 + arow];
        #pragma unroll
        for (int r = 0; r < 4; ++r) {
            const int prow = hi * 4 + r;
            out[((size_t)(pt0 + prow)) * 64 + w * 16 + arow] = acc[r] + bvs;
        }
    }
}

extern "C" void kernel_launch(void* const* d_in, const int* in_sizes, int n_in,
                              void* d_out, int out_size, void* d_ws, size_t ws_size,
                              hipStream_t stream) {
    const float* inp      = (const float*)d_in[0];
    const float* points   = (const float*)d_in[1];
    const float* next_pts = (const float*)d_in[2];
    const int*   indices  = (const int*)  d_in[3];
    const float* weight   = (const float*)d_in[4];
    const float* bias     = (const float*)d_in[5];
    const float* centers  = (const float*)d_in[6];
    const float* l1w      = (const float*)d_in[7];
    const float* l1b      = (const float*)d_in[8];
    const float* l2w      = (const float*)d_in[9];
    const float* l2b      = (const float*)d_in[10];
    const float* l3w      = (const float*)d_in[11];
    const float* l3b      = (const float*)d_in[12];
    float* outp = (float*)d_out;

    unsigned short* Wt    = (unsigned short*)d_ws;                  // 128 KB @ 0
    float*          A1f   = (float*)((char*)d_ws + 131072);         // 512 B
    unsigned short* inpbf = (unsigned short*)((char*)d_ws + (1 << 20)); // 4 MB @ 1 MB

    prep_all<<<8449, 256, 0, stream>>>(inp, inpbf, weight, Wt,
                                       l1w, l1b, centers, A1f);

    const int grid = (BB * NN) / P;               // 2048 blocks
    ptconv_fused<<<grid, 256, 0, stream>>>(inpbf, points, next_pts, indices,
                                           Wt, A1f, bias,
                                           l2w, l2b, l3w, l3b, outp);
}

// Round 15
// 54.506 us; speedup vs baseline: 1.0464x; 1.0464x over previous
//
#include <hip/hip_runtime.h>

#define BB    4
#define NN    8192
#define KK    16
#define CIN   64
#define COUTC 64
#define P     32           // points per block = two 16-point MFMA M-tiles

typedef short bf16x8 __attribute__((ext_vector_type(8)));
typedef float f32x4  __attribute__((ext_vector_type(4)));
typedef float f32x2  __attribute__((ext_vector_type(2)));
typedef unsigned short u16x4 __attribute__((ext_vector_type(4)));

__device__ __forceinline__ unsigned short f2bf_rne(float f) {
    unsigned int u = __builtin_bit_cast(unsigned int, f);
    u += 0x7fffu + ((u >> 16) & 1u);
    return (unsigned short)(u >> 16);
}

__device__ __forceinline__ unsigned int pack_bf2(float lo, float hi) {
    return (unsigned int)f2bf_rne(lo) | ((unsigned int)f2bf_rne(hi) << 16);
}

// ---- fused prep: [0,8192) inp->bf16 tile-transposed ; [8192,8448) Wt ; 8448 fold ----
// inp_bf[n*64 + r*4 + t4] = inp[n*64 + t4*16 + r]  (r=cin%16, t4=cin/16)
__global__ __launch_bounds__(256) void prep_all(
    const float* __restrict__ inp, unsigned short* __restrict__ inp_bf,
    const float* __restrict__ W, unsigned short* __restrict__ Wt,
    const float* __restrict__ l1w, const float* __restrict__ l1b,
    const float* __restrict__ centers, float* __restrict__ A1)
{
    const int blk = blockIdx.x;
    const int t   = threadIdx.x;
    if (blk < 8192) {
        const int o  = blk * 256 + t;                  // 2M total
        const int n  = o >> 6;
        const int q  = o & 63;
        const int r  = q >> 2;
        const int t4 = q & 3;
        inp_bf[o] = f2bf_rne(inp[n * 64 + t4 * 16 + r]);
    } else if (blk < 8448) {
        const int o    = (blk - 8192) * 256 + t;       // 65536 total
        const int cout = o >> 10;
        const int kp   = o & 1023;
        const int m    = kp >> 6;
        const int cin  = kp & 63;
        Wt[o] = f2bf_rne(W[(cin * 16 + m) * 64 + cout] * (1.0f / 16.0f));
    } else if (t < 32) {
        float bb = l1b[t];
        float a0 = 0.f, a1 = 0.f, a2 = 0.f;
        for (int c = 0; c < 16; ++c) {
            const float w0 = l1w[(c     ) * 32 + t];
            const float w1 = l1w[(16 + c) * 32 + t];
            const float w2 = l1w[(32 + c) * 32 + t];
            a0 += w0; a1 += w1; a2 += w2;
            bb -= centers[c] * w0 + centers[16 + c] * w1 + centers[32 + c] * w2;
        }
        A1[0 * 32 + t] = a0; A1[1 * 32 + t] = a1; A1[2 * 32 + t] = a2; A1[3 * 32 + t] = bb;
    }
}

__global__ __launch_bounds__(256, 2) void ptconv_fused(
    const unsigned short* __restrict__ inp_bf, // [B,N,16,4] bf16 tile-transposed (prep)
    const float* __restrict__ points,    // [B,N,3]
    const float* __restrict__ next_pts,  // [B,N,3]
    const int*   __restrict__ indices,   // [B,N,K]
    const unsigned short* __restrict__ Wt, // [COUT][1024] bf16 (prep)
    const float* __restrict__ A1f,       // [4][32] folded layer-1 (prep, SoA)
    const float* __restrict__ bias,      // [COUT]
    const float* __restrict__ l2w, const float* __restrict__ l2b,  // [32,16],[16]
    const float* __restrict__ l3w, const float* __restrict__ l3b,  // [16,16],[16]
    float* __restrict__ out)             // [B,N,COUT]
{
    const int t    = threadIdx.x;
    const int lane = t & 63;
    const int w    = t >> 6;             // wave id 0..3
    const int pt0  = blockIdx.x * P;
    const int b    = pt0 >> 13;          // pt0 / NN

    // 32 windows of 1024 B. Per point p:
    //  - phase 1 (wave w writes windows w*8..w*8+7 ONLY) stores h3t[p] (512 B,
    //    layout m*32+k*2, XOR (p&3)<<5);
    //  - phase 2 (same wave) reads h3t[p] then overwrites the window with f[p]'s
    //    even-cin half (1024 B, XOR ((p&7)^(m&7))<<4). Same array + same wave =>
    //    ds order preserved (may-alias) and HW in-order.
    __shared__ unsigned short s_u[P][512];        // 32 KB -> 4 blocks/CU

    const f32x2 zero2 = {0.f, 0.f};

    // ---------------- phase 1: MLP packed f32; 1 point x 2 k's per thread ----------------
    {
        const int p  = w * 8 + (lane >> 3);    // wave w owns windows w*8..w*8+7
        const int kb = lane & 7;
        const int pt = pt0 + p;
        const float* np = next_pts + (size_t)pt * 3;
        const float nx = np[0], ny = np[1], nz = np[2];

        const f32x2* A0  = (const f32x2*)(A1f);
        const f32x2* A1v = (const f32x2*)(A1f + 32);
        const f32x2* A2  = (const f32x2*)(A1f + 64);
        const f32x2* A3  = (const f32x2*)(A1f + 96);

        #pragma unroll
        for (int ii = 0; ii < 2; ++ii) {
            const int k  = kb + ii * 8;
            const int id = indices[(size_t)pt0 * KK + p * 16 + k];
            const float* pp = points + ((size_t)(b * NN + id)) * 3;
            const float px = pp[0] - nx;
            const float py = pp[1] - ny;
            const float pz = pp[2] - nz;
            const f32x2 px2 = {px, px}, py2 = {py, py}, pz2 = {pz, pz};

            f32x2 h1[16];
            #pragma unroll
            for (int j = 0; j < 16; ++j) {
                f32x2 a = __builtin_elementwise_fma(pz2, A2[j], A3[j]);
                a = __builtin_elementwise_fma(py2, A1v[j], a);
                a = __builtin_elementwise_fma(px2, A0[j], a);
                h1[j] = __builtin_elementwise_max(a, zero2);
            }

            f32x2 h2[8];
            {
                const f32x2* b2p = (const f32x2*)l2b;
                #pragma unroll
                for (int j = 0; j < 8; ++j) h2[j] = b2p[j];
            }
            #pragma unroll
            for (int i = 0; i < 32; ++i) {
                const float hv = h1[i >> 1][i & 1];
                const f32x2 hvv = {hv, hv};
                const f32x2* wr = (const f32x2*)(l2w + i * 16);   // uniform -> s_load
                #pragma unroll
                for (int j = 0; j < 8; ++j)
                    h2[j] = __builtin_elementwise_fma(hvv, wr[j], h2[j]);
            }
            #pragma unroll
            for (int j = 0; j < 8; ++j) h2[j] = __builtin_elementwise_max(h2[j], zero2);

            f32x2 h3v[8];
            {
                const f32x2* b3p = (const f32x2*)l3b;
                #pragma unroll
                for (int j = 0; j < 8; ++j) h3v[j] = b3p[j];
            }
            #pragma unroll
            for (int i = 0; i < 16; ++i) {
                const float hv = h2[i >> 1][i & 1];
                const f32x2 hvv = {hv, hv};
                const f32x2* wr = (const f32x2*)(l3w + i * 16);   // uniform -> s_load
                #pragma unroll
                for (int j = 0; j < 8; ++j)
                    h3v[j] = __builtin_elementwise_fma(hvv, wr[j], h3v[j]);
            }
            char* ub = (char*)s_u;
            const unsigned int hsw = ((unsigned)(p & 3)) << 5;
            #pragma unroll
            for (int j = 0; j < 8; ++j) {
                const f32x2 v = __builtin_elementwise_max(h3v[j], zero2);
                const unsigned int b0 = ((unsigned)(p * 1024 + (2 * j    ) * 32 + k * 2)) ^ hsw;
                const unsigned int b1 = ((unsigned)(p * 1024 + (2 * j + 1) * 32 + k * 2)) ^ hsw;
                *(unsigned short*)(ub + b0) = f2bf_rne(v[0]);
                *(unsigned short*)(ub + b1) = f2bf_rne(v[1]);
            }
        }
    }
    // wave w's phase 2 reads only windows w*8..w*8+7, written above by wave w itself.
    __threadfence_block();

    // ---------------- phase 2: f = feats @ h3 via MFMA; 4 point-pair groups per wave ----------------
    uint2 holdA[4][2], holdB[4][2];          // odd-cin halves, static-indexed (unrolled)
    {
        const int arow = lane & 15;          // A-row = cin_local ; B-col = m
        const int hi   = lane >> 4;
        const int kg   = (hi & 1) * 8;       // k-group base within the 16 real k
        const unsigned short* ibase = inp_bf + (size_t)b * NN * 64;
        const int* idxg = indices + (size_t)pt0 * KK;
        const bf16x8 vzero = {0, 0, 0, 0, 0, 0, 0, 0};
        char* fbb = (char*)s_u;

        #pragma unroll
        for (int pr = 0; pr < 4; ++pr) {
            const int pA  = w * 8 + pr * 2;
            const int pB  = pA + 1;
            const int myp = (hi < 2) ? pA : pB;

            const int4 i0 = *(const int4*)&idxg[myp * 16 + kg];
            const int4 i1 = *(const int4*)&idxg[myp * 16 + kg + 4];
            const int ids[8] = {i0.x, i0.y, i0.z, i0.w, i1.x, i1.y, i1.z, i1.w};

            u16x4 rows[8];
            #pragma unroll
            for (int jj = 0; jj < 8; ++jj)
                rows[jj] = *(const u16x4*)(ibase + (size_t)ids[jj] * 64 + arow * 4);

            // read h3t BEFORE overwriting this window with f
            const unsigned int hb = ((unsigned)(myp * 1024 + arow * 32 + kg * 2))
                                    ^ (((unsigned)(myp & 3)) << 5);
            const bf16x8 vfull = *(const bf16x8*)((const char*)s_u + hb);
            const bf16x8 bfA = (hi < 2) ? vfull : vzero;
            const bf16x8 bfB = (hi < 2) ? vzero : vfull;

            #pragma unroll
            for (int tile = 0; tile < 4; ++tile) {
                bf16x8 af;
                #pragma unroll
                for (int jj = 0; jj < 8; ++jj) af[jj] = (short)rows[jj][tile];
                const f32x4 z4 = {0.f, 0.f, 0.f, 0.f};
                const f32x4 dA = __builtin_amdgcn_mfma_f32_16x16x32_bf16(af, bfA, z4, 0, 0, 0);
                const f32x4 dB = __builtin_amdgcn_mfma_f32_16x16x32_bf16(af, bfB, z4, 0, 0, 0);
                const uint2 vA = make_uint2(pack_bf2(dA[0], dA[1]), pack_bf2(dA[2], dA[3]));
                const uint2 vB = make_uint2(pack_bf2(dB[0], dB[1]), pack_bf2(dB[2], dB[3]));
                if (tile < 2) {
                    const unsigned int baseo = (unsigned)(arow * 64 + tile * 32 + hi * 8);
                    const unsigned int offA = ((unsigned)(pA * 1024) + baseo)
                                              ^ (((unsigned)((pA & 7) ^ (arow & 7))) << 4);
                    const unsigned int offB = ((unsigned)(pB * 1024) + baseo)
                                              ^ (((unsigned)((pB & 7) ^ (arow & 7))) << 4);
                    *(uint2*)(fbb + offA) = vA;
                    *(uint2*)(fbb + offB) = vB;
                } else {
                    holdA[pr][tile - 2] = vA;
                    holdB[pr][tile - 2] = vB;
                }
            }
        }
    }
    __syncthreads();

    // ---------------- phase 3: even k-pass (both sub-tiles), swap halves, odd k-pass ----------------
    {
        const int arow = lane & 15;      // A row = point-local ; B col = cout_local
        const int hi   = lane >> 4;
        const unsigned short* wb = Wt + (size_t)(w * 16 + arow) * 1024 + hi * 8;
        const char* fbb = (const char*)s_u;
        f32x4 acc0 = {0.f, 0.f, 0.f, 0.f};
        f32x4 acc1 = {0.f, 0.f, 0.f, 0.f};

        #pragma unroll
        for (int m = 0; m < 16; ++m) {   // even kk = 2m  (cin 0..31)
            const unsigned int xr = ((unsigned)((arow & 7) ^ (m & 7))) << 4;
            const bf16x8 bv  = *(const bf16x8*)(wb + m * 64);
            const bf16x8 av0 = *(const bf16x8*)(fbb +
                (((unsigned)(arow * 1024 + m * 64 + hi * 16)) ^ xr));
            const bf16x8 av1 = *(const bf16x8*)(fbb +
                (((unsigned)((16 + arow) * 1024 + m * 64 + hi * 16)) ^ xr));
            acc0 = __builtin_amdgcn_mfma_f32_16x16x32_bf16(av0, bv, acc0, 0, 0, 0);
            acc1 = __builtin_amdgcn_mfma_f32_16x16x32_bf16(av1, bv, acc1, 0, 0, 0);
        }
        __syncthreads();                 // even halves fully read (all windows)

        {   // write odd halves (cin 32..63) from hold regs
            char* fbw = (char*)s_u;
            #pragma unroll
            for (int pr = 0; pr < 4; ++pr) {
                const int pA = w * 8 + pr * 2;
                const int pB = pA + 1;
                #pragma unroll
                for (int t2 = 0; t2 < 2; ++t2) {
                    const unsigned int baseo = (unsigned)(arow * 64 + t2 * 32 + hi * 8);
                    const unsigned int offA = ((unsigned)(pA * 1024) + baseo)
                                              ^ (((unsigned)((pA & 7) ^ (arow & 7))) << 4);
                    const unsigned int offB = ((unsigned)(pB * 1024) + baseo)
                                              ^ (((unsigned)((pB & 7) ^ (arow & 7))) << 4);
                    *(uint2*)(fbw + offA) = holdA[pr][t2];
                    *(uint2*)(fbw + offB) = holdB[pr][t2];
                }
            }
        }
        __syncthreads();                 // odd halves visible

        #pragma unroll
        for (int m = 0; m < 16; ++m) {   // odd kk = 2m+1  (cin 32..63)
            const unsigned int xr = ((unsigned)((arow & 7) ^ (m & 7))) << 4;
            const bf16x8 bv  = *(const bf16x8*)(wb + m * 64 + 32);
            const bf16x8 av0 = *(const bf16x8*)(fbb +
                (((unsigned)(arow * 1024 + m * 64 + hi * 16)) ^ xr));
            const bf16x8 av1 = *(const bf16x8*)(fbb +
                (((unsigned)((16 + arow) * 1024 + m * 64 + hi * 16)) ^ xr));
            acc0 = __builtin_amdgcn_mfma_f32_16x16x32_bf16(av0, bv, acc0, 0, 0, 0);
            acc1 = __builtin_amdgcn_mfma_f32_16x16x32_bf16(av1, bv, acc1, 0, 0, 0);
        }

        const float bvs = bias[w * 16 + arow];
        #pragma unroll
        for (int r = 0; r < 4; ++r) {
            const int prow = hi * 4 + r;
            out[((size_t)(pt0 + prow)) * 64 + w * 16 + arow]      = acc0[r] + bvs;
            out[((size_t)(pt0 + 16 + prow)) * 64 + w * 16 + arow] = acc1[r] + bvs;
        }
    }
}

extern "C" void kernel_launch(void* const* d_in, const int* in_sizes, int n_in,
                              void* d_out, int out_size, void* d_ws, size_t ws_size,
                              hipStream_t stream) {
    const float* inp      = (const float*)d_in[0];
    const float* points   = (const float*)d_in[1];
    const float* next_pts = (const float*)d_in[2];
    const int*   indices  = (const int*)  d_in[3];
    const float* weight   = (const float*)d_in[4];
    const float* bias     = (const float*)d_in[5];
    const float* centers  = (const float*)d_in[6];
    const float* l1w      = (const float*)d_in[7];
    const float* l1b      = (const float*)d_in[8];
    const float* l2w      = (const float*)d_in[9];
    const float* l2b      = (const float*)d_in[10];
    const float* l3w      = (const float*)d_in[11];
    const float* l3b      = (const float*)d_in[12];
    float* outp = (float*)d_out;

    unsigned short* Wt    = (unsigned short*)d_ws;                  // 128 KB @ 0
    float*          A1f   = (float*)((char*)d_ws + 131072);         // 512 B
    unsigned short* inpbf = (unsigned short*)((char*)d_ws + (1 << 20)); // 4 MB @ 1 MB

    prep_all<<<8449, 256, 0, stream>>>(inp, inpbf, weight, Wt,
                                       l1w, l1b, centers, A1f);

    const int grid = (BB * NN) / P;               // 1024 blocks
    ptconv_fused<<<grid, 256, 0, stream>>>(inpbf, points, next_pts, indices,
                                           Wt, A1f, bias,
                                           l2w, l2b, l3w, l3b, outp);
}

// Round 17
// 53.130 us; speedup vs baseline: 1.0734x; 1.0259x over previous
//
#include <hip/hip_runtime.h>

#define BB    4
#define NN    8192
#define KK    16
#define CIN   64
#define COUTC 64
#define P     16           // points per block (= MFMA M-tile)

typedef short bf16x8 __attribute__((ext_vector_type(8)));
typedef float f32x4  __attribute__((ext_vector_type(4)));
typedef float f32x2  __attribute__((ext_vector_type(2)));
typedef unsigned short u16x4 __attribute__((ext_vector_type(4)));

__device__ __forceinline__ unsigned short f2bf_rne(float f) {
    unsigned int u = __builtin_bit_cast(unsigned int, f);
    u += 0x7fffu + ((u >> 16) & 1u);
    return (unsigned short)(u >> 16);
}

__device__ __forceinline__ unsigned int pack_bf2(float lo, float hi) {
    return (unsigned int)f2bf_rne(lo) | ((unsigned int)f2bf_rne(hi) << 16);
}

// ---- fused prep ----
// [0,8192): inp->bf16 tile-transposed: inp_bf[n*64 + r*4 + t4] = inp[n*64 + t4*16 + r]
// [8192,8448): Wt (phase-3 B); 8448: layer-1 fold; 8449: Wt2/Wt3 lane-major MFMA B-frags
__global__ __launch_bounds__(256) void prep_all(
    const float* __restrict__ inp, unsigned short* __restrict__ inp_bf,
    const float* __restrict__ W, unsigned short* __restrict__ Wt,
    const float* __restrict__ l1w, const float* __restrict__ l1b,
    const float* __restrict__ centers, float* __restrict__ A1,
    const float* __restrict__ l2w, const float* __restrict__ l3w,
    unsigned short* __restrict__ Wt2, unsigned short* __restrict__ Wt3)
{
    const int blk = blockIdx.x;
    const int t   = threadIdx.x;
    if (blk < 8192) {
        const int o  = blk * 256 + t;                  // 2M total
        const int n  = o >> 6;
        const int q  = o & 63;
        const int r  = q >> 2;
        const int t4 = q & 3;
        inp_bf[o] = f2bf_rne(inp[n * 64 + t4 * 16 + r]);
    } else if (blk < 8448) {
        const int o    = (blk - 8192) * 256 + t;       // 65536 total
        const int cout = o >> 10;
        const int kp   = o & 1023;
        const int m    = kp >> 6;
        const int cin  = kp & 63;
        Wt[o] = f2bf_rne(W[(cin * 16 + m) * 64 + cout] * (1.0f / 16.0f));
    } else if (blk == 8448) {
        if (t < 32) {
            float bb = l1b[t];
            float a0 = 0.f, a1 = 0.f, a2 = 0.f;
            for (int c = 0; c < 16; ++c) {
                const float w0 = l1w[(c     ) * 32 + t];
                const float w1 = l1w[(16 + c) * 32 + t];
                const float w2 = l1w[(32 + c) * 32 + t];
                a0 += w0; a1 += w1; a2 += w2;
                bb -= centers[c] * w0 + centers[16 + c] * w1 + centers[32 + c] * w2;
            }
            A1[0 * 32 + t] = a0; A1[1 * 32 + t] = a1; A1[2 * 32 + t] = a2; A1[3 * 32 + t] = bb;
        }
    } else {
        // Wt2[l*8+j] = l2w[k][col], k=(l>>4)*8+j, col=l&15   (B-frag, K=32)
        // Wt3[l*8+j] = k<16 ? l3w[k][col] : 0                (B-frag, K=16 zero-padded)
        for (int i = t; i < 1024; i += 256) {
            if (i < 512) {
                const int l = i >> 3, j = i & 7;
                const int k = (l >> 4) * 8 + j, col = l & 15;
                Wt2[i] = f2bf_rne(l2w[k * 16 + col]);
            } else {
                const int i3 = i - 512;
                const int l = i3 >> 3, j = i3 & 7;
                const int k = (l >> 4) * 8 + j, col = l & 15;
                Wt3[i3] = (k < 16) ? f2bf_rne(l3w[k * 16 + col]) : (unsigned short)0;
            }
        }
    }
}

__global__ __launch_bounds__(256, 2) void ptconv_fused(
    const unsigned short* __restrict__ inp_bf, // [B,N,16,4] bf16 tile-transposed (prep)
    const float* __restrict__ points,    // [B,N,3]
    const float* __restrict__ next_pts,  // [B,N,3]
    const int*   __restrict__ indices,   // [B,N,K]
    const unsigned short* __restrict__ Wt,  // [COUT][1024] bf16 (prep)
    const unsigned short* __restrict__ Wt2, // [64][8] bf16 layer-2 B-frag
    const unsigned short* __restrict__ Wt3, // [64][8] bf16 layer-3 B-frag (zero-pad)
    const float* __restrict__ A1f,       // [4][32] folded layer-1 (prep, SoA)
    const float* __restrict__ bias,      // [COUT]
    const float* __restrict__ l2b, const float* __restrict__ l3b,
    float* __restrict__ out)             // [B,N,COUT]
{
    const int t    = threadIdx.x;
    const int lane = t & 63;
    const int w    = t >> 6;             // wave id 0..3
    const int pt0  = blockIdx.x * P;
    const int b    = pt0 >> 13;          // pt0 / NN

    // ONE 16 KB buffer; wave w owns bytes [w*4096, (w+1)*4096) until the phase-3 barrier.
    // Lifecycle (strict same-wave read -> fence -> overwrite, single may-alias array):
    //   H1 rows (64B/row, key (row&3)<<4)  ->  L2 A-reads  -> fence -> H2 overlay (32B/row)
    //   ->  L3 A-reads  -> fence ->  h3t windows overlay  ->  phase-2 reads
    //   ->  f even-half overlay.  Phase 3 reads cross-wave after barrier.
    __shared__ unsigned short s_u[P][512];        // 16 KB

    char* const wb = (char*)s_u + w * 4096;       // wave region base
    const f32x2 zero2 = {0.f, 0.f};
    const f32x4 z4 = {0.f, 0.f, 0.f, 0.f};
    const int arow = lane & 15;
    const int hi   = lane >> 4;

    // ---------------- stage 1a: h1 per thread (row = t = p*16+k), pack, H1 -> LDS ----------------
    {
        const int p = t >> 4;
        const int pt = pt0 + p;
        const int id = indices[(size_t)pt0 * KK + t];  // coalesced
        const float* pp = points + ((size_t)(b * NN + id)) * 3;
        const float* np = next_pts + (size_t)pt * 3;
        const float px = pp[0] - np[0];
        const float py = pp[1] - np[1];
        const float pz = pp[2] - np[2];
        const f32x2 px2 = {px, px}, py2 = {py, py}, pz2 = {pz, pz};

        const f32x2* A0  = (const f32x2*)(A1f);
        const f32x2* A1v = (const f32x2*)(A1f + 32);
        const f32x2* A2  = (const f32x2*)(A1f + 64);
        const f32x2* A3  = (const f32x2*)(A1f + 96);
        unsigned int pk[16];
        #pragma unroll
        for (int j = 0; j < 16; ++j) {
            f32x2 a = __builtin_elementwise_fma(pz2, A2[j], A3[j]);
            a = __builtin_elementwise_fma(py2, A1v[j], a);
            a = __builtin_elementwise_fma(px2, A0[j], a);
            a = __builtin_elementwise_max(a, zero2);
            pk[j] = pack_bf2(a[0], a[1]);          // h1 units 2j, 2j+1 (bf16)
        }
        // H1 row r'=lane, chunk c (units 8c..8c+7): addr = r'*64 + (c*16 ^ ((r'&3)<<4))
        // key uses bits 4-5 ONLY -> stays inside the 64-B row (r16 bug: (r'&7)<<4 set bit 6)
        #pragma unroll
        for (int c = 0; c < 4; ++c) {
            const unsigned int off = (unsigned)(lane * 64)
                + ((((unsigned)c) * 16u) ^ (((unsigned)(lane & 3)) << 4));
            *(uint4*)(wb + off) = make_uint4(pk[4*c], pk[4*c+1], pk[4*c+2], pk[4*c+3]);
        }
    }
    __threadfence_block();

    // ---------------- stage 1b: layer 2 via MFMA (4 row-tiles); defer H2 overlay ----------------
    {
        const bf16x8 b2 = *(const bf16x8*)(Wt2 + lane * 8);
        const float bias2 = l2b[arow];             // D col = l&15 = h2 unit
        uint2 h2sv[4];
        #pragma unroll
        for (int T = 0; T < 4; ++T) {
            const int row = T * 16 + arow;         // local row, k-slice = hi
            const unsigned int off = (unsigned)(row * 64)
                + ((((unsigned)hi) * 16u) ^ (((unsigned)(row & 3)) << 4));
            const bf16x8 a = *(const bf16x8*)(wb + off);
            const f32x4 d = __builtin_amdgcn_mfma_f32_16x16x32_bf16(a, b2, z4, 0, 0, 0);
            h2sv[T].x = pack_bf2(fmaxf(d[0] + bias2, 0.f), fmaxf(d[1] + bias2, 0.f));
            h2sv[T].y = pack_bf2(fmaxf(d[2] + bias2, 0.f), fmaxf(d[3] + bias2, 0.f));
        }
        __threadfence_block();                     // all H1 reads retired before H2 overlay
        // D: unit=arow, local rows T*16 + hi*4 + reg.  H2: (R*32 + u*2) ^ ((R&1)<<4)
        #pragma unroll
        for (int T = 0; T < 4; ++T) {
            const unsigned short v0 = (unsigned short)(h2sv[T].x & 0xffffu);
            const unsigned short v1 = (unsigned short)(h2sv[T].x >> 16);
            const unsigned short v2 = (unsigned short)(h2sv[T].y & 0xffffu);
            const unsigned short v3 = (unsigned short)(h2sv[T].y >> 16);
            const int R0 = T * 16 + hi * 4;
            *(unsigned short*)(wb + ((unsigned)((R0+0) * 32 + arow * 2) ^ (((unsigned)((R0+0) & 1)) << 4))) = v0;
            *(unsigned short*)(wb + ((unsigned)((R0+1) * 32 + arow * 2) ^ (((unsigned)((R0+1) & 1)) << 4))) = v1;
            *(unsigned short*)(wb + ((unsigned)((R0+2) * 32 + arow * 2) ^ (((unsigned)((R0+2) & 1)) << 4))) = v2;
            *(unsigned short*)(wb + ((unsigned)((R0+3) * 32 + arow * 2) ^ (((unsigned)((R0+3) & 1)) << 4))) = v3;
        }
    }
    __threadfence_block();

    // ---------------- stage 1d/1e: layer 3 via MFMA (K zero-padded), h3t overlay ----------------
    {
        const bf16x8 b3 = *(const bf16x8*)(Wt3 + lane * 8);   // zeros for k>=16
        const float bias3 = l3b[arow];
        uint2 hsave[4];                             // defer writes until all H2 reads done
        #pragma unroll
        for (int T = 0; T < 4; ++T) {
            const int row = T * 16 + arow;
            const unsigned int off = ((unsigned)(row * 32 + hi * 16)) ^ (((unsigned)(row & 1)) << 4);
            const bf16x8 a = *(const bf16x8*)(wb + off);      // hi>=2 reads junk; b3=0 there
            const f32x4 d = __builtin_amdgcn_mfma_f32_16x16x32_bf16(a, b3, z4, 0, 0, 0);
            hsave[T].x = pack_bf2(fmaxf(d[0] + bias3, 0.f), fmaxf(d[1] + bias3, 0.f));
            hsave[T].y = pack_bf2(fmaxf(d[2] + bias3, 0.f), fmaxf(d[3] + bias3, 0.f));
        }
        __threadfence_block();                      // all H2 reads retired before h3t overlay
        // h3t: window p=w*4+T, byte m*32 + k*2 ^ ((p&3)<<5); m=arow, k = hi*4+reg
        #pragma unroll
        for (int T = 0; T < 4; ++T) {
            const unsigned int xw = ((unsigned)(T & 3)) << 5;
            const unsigned short h0  = (unsigned short)(hsave[T].x & 0xffffu);
            const unsigned short h1v = (unsigned short)(hsave[T].x >> 16);
            const unsigned short h2v = (unsigned short)(hsave[T].y & 0xffffu);
            const unsigned short h3v = (unsigned short)(hsave[T].y >> 16);
            const unsigned int base = (unsigned)(T * 1024 + arow * 32 + hi * 8);
            *(unsigned short*)(wb + ((base + 0) ^ xw)) = h0;
            *(unsigned short*)(wb + ((base + 2) ^ xw)) = h1v;
            *(unsigned short*)(wb + ((base + 4) ^ xw)) = h2v;
            *(unsigned short*)(wb + ((base + 6) ^ xw)) = h3v;
        }
    }
    __threadfence_block();

    // ---------------- phase 2: f = feats @ h3 via MFMA (r14 verbatim) ----------------
    uint2 holdA[2][2], holdB[2][2];
    {
        const int kg   = (hi & 1) * 8;
        const unsigned short* ibase = inp_bf + (size_t)b * NN * 64;
        const int* idxg = indices + (size_t)pt0 * KK;
        const bf16x8 vzero = {0, 0, 0, 0, 0, 0, 0, 0};
        char* fbb = (char*)s_u;

        #pragma unroll
        for (int pr = 0; pr < 2; ++pr) {
            const int pA  = w * 4 + pr * 2;
            const int pB  = pA + 1;
            const int myp = (hi < 2) ? pA : pB;

            const int4 i0 = *(const int4*)&idxg[myp * 16 + kg];
            const int4 i1 = *(const int4*)&idxg[myp * 16 + kg + 4];
            const int ids[8] = {i0.x, i0.y, i0.z, i0.w, i1.x, i1.y, i1.z, i1.w};

            u16x4 rows[8];
            #pragma unroll
            for (int jj = 0; jj < 8; ++jj)
                rows[jj] = *(const u16x4*)(ibase + (size_t)ids[jj] * 64 + arow * 4);

            const unsigned int hb = ((unsigned)(myp * 1024 + arow * 32 + kg * 2))
                                    ^ (((unsigned)(myp & 3)) << 5);
            const bf16x8 vfull = *(const bf16x8*)((const char*)s_u + hb);
            const bf16x8 bfA = (hi < 2) ? vfull : vzero;
            const bf16x8 bfB = (hi < 2) ? vzero : vfull;

            #pragma unroll
            for (int tile = 0; tile < 4; ++tile) {
                bf16x8 af;
                #pragma unroll
                for (int jj = 0; jj < 8; ++jj) af[jj] = (short)rows[jj][tile];
                const f32x4 dA = __builtin_amdgcn_mfma_f32_16x16x32_bf16(af, bfA, z4, 0, 0, 0);
                const f32x4 dB = __builtin_amdgcn_mfma_f32_16x16x32_bf16(af, bfB, z4, 0, 0, 0);
                const uint2 vA = make_uint2(pack_bf2(dA[0], dA[1]), pack_bf2(dA[2], dA[3]));
                const uint2 vB = make_uint2(pack_bf2(dB[0], dB[1]), pack_bf2(dB[2], dB[3]));
                if (tile < 2) {
                    const unsigned int baseo = (unsigned)(arow * 64 + tile * 32 + hi * 8);
                    const unsigned int offA = ((unsigned)(pA * 1024) + baseo)
                                              ^ (((unsigned)((pA & 7) ^ (arow & 7))) << 4);
                    const unsigned int offB = ((unsigned)(pB * 1024) + baseo)
                                              ^ (((unsigned)((pB & 7) ^ (arow & 7))) << 4);
                    *(uint2*)(fbb + offA) = vA;
                    *(uint2*)(fbb + offB) = vB;
                } else {
                    holdA[pr][tile - 2] = vA;
                    holdB[pr][tile - 2] = vB;
                }
            }
        }
    }
    __syncthreads();

    // ---------------- phase 3: even k-pass, swap halves, odd k-pass (r14 verbatim) ----------------
    {
        const unsigned short* wtb = Wt + (size_t)(w * 16 + arow) * 1024 + hi * 8;
        const char* fbb = (const char*)s_u;
        f32x4 acc = {0.f, 0.f, 0.f, 0.f};

        #pragma unroll
        for (int m = 0; m < 16; ++m) {   // even kk = 2m  (cin 0..31)
            const unsigned int xr = ((unsigned)((arow & 7) ^ (m & 7))) << 4;
            const bf16x8 av = *(const bf16x8*)(fbb +
                (((unsigned)(arow * 1024 + m * 64 + hi * 16)) ^ xr));
            const bf16x8 bv = *(const bf16x8*)(wtb + m * 64);
            acc = __builtin_amdgcn_mfma_f32_16x16x32_bf16(av, bv, acc, 0, 0, 0);
        }
        __syncthreads();

        {   // write odd half (cin 32..63) from hold regs
            char* fbw = (char*)s_u;
            #pragma unroll
            for (int pr = 0; pr < 2; ++pr) {
                const int pA = w * 4 + pr * 2;
                const int pB = pA + 1;
                #pragma unroll
                for (int t2 = 0; t2 < 2; ++t2) {
                    const unsigned int baseo = (unsigned)(arow * 64 + t2 * 32 + hi * 8);
                    const unsigned int offA = ((unsigned)(pA * 1024) + baseo)
                                              ^ (((unsigned)((pA & 7) ^ (arow & 7))) << 4);
                    const unsigned int offB = ((unsigned)(pB * 1024) + baseo)
                                              ^ (((unsigned)((pB & 7) ^ (arow & 7))) << 4);
                    *(uint2*)(fbw + offA) = holdA[pr][t2];
                    *(uint2*)(fbw + offB) = holdB[pr][t2];
                }
            }
        }
        __syncthreads();

        #pragma unroll
        for (int m = 0; m < 16; ++m) {   // odd kk = 2m+1  (cin 32..63)
            const unsigned int xr = ((unsigned)((arow & 7) ^ (m & 7))) << 4;
            const bf16x8 av = *(const bf16x8*)(fbb +
                (((unsigned)(arow * 1024 + m * 64 + hi * 16)) ^ xr));
            const bf16x8 bv = *(const bf16x8*)(wtb + m * 64 + 32);
            acc = __builtin_amdgcn_mfma_f32_16x16x32_bf16(av, bv, acc, 0, 0, 0);
        }

        const float bvs = bias[w * 16 + arow];
        #pragma unroll
        for (int r = 0; r < 4; ++r) {
            const int prow = hi * 4 + r;
            out[((size_t)(pt0 + prow)) * 64 + w * 16 + arow] = acc[r] + bvs;
        }
    }
}

extern "C" void kernel_launch(void* const* d_in, const int* in_sizes, int n_in,
                              void* d_out, int out_size, void* d_ws, size_t ws_size,
                              hipStream_t stream) {
    const float* inp      = (const float*)d_in[0];
    const float* points   = (const float*)d_in[1];
    const float* next_pts = (const float*)d_in[2];
    const int*   indices  = (const int*)  d_in[3];
    const float* weight   = (const float*)d_in[4];
    const float* bias     = (const float*)d_in[5];
    const float* centers  = (const float*)d_in[6];
    const float* l1w      = (const float*)d_in[7];
    const float* l1b      = (const float*)d_in[8];
    const float* l2w      = (const float*)d_in[9];
    const float* l2b      = (const float*)d_in[10];
    const float* l3w      = (const float*)d_in[11];
    const float* l3b      = (const float*)d_in[12];
    float* outp = (float*)d_out;

    unsigned short* Wt    = (unsigned short*)d_ws;                  // 128 KB @ 0
    float*          A1f   = (float*)((char*)d_ws + 131072);         // 512 B
    unsigned short* Wt2   = (unsigned short*)((char*)d_ws + 132096);// 1 KB
    unsigned short* Wt3   = (unsigned short*)((char*)d_ws + 133120);// 1 KB
    unsigned short* inpbf = (unsigned short*)((char*)d_ws + (1 << 20)); // 4 MB @ 1 MB

    prep_all<<<8450, 256, 0, stream>>>(inp, inpbf, weight, Wt,
                                       l1w, l1b, centers, A1f,
                                       l2w, l3w, Wt2, Wt3);

    const int grid = (BB * NN) / P;               // 2048 blocks
    ptconv_fused<<<grid, 256, 0, stream>>>(inpbf, points, next_pts, indices,
                                           Wt, Wt2, Wt3, A1f, bias,
                                           l2b, l3b, outp);
}

// Round 18
// 52.654 us; speedup vs baseline: 1.0832x; 1.0090x over previous
//
#include <hip/hip_runtime.h>

#define BB    4
#define NN    8192
#define KK    16
#define CIN   64
#define COUTC 64
#define P     16           // points per block (= MFMA M-tile)

typedef short bf16x8 __attribute__((ext_vector_type(8)));
typedef float f32x4  __attribute__((ext_vector_type(4)));
typedef float f32x2  __attribute__((ext_vector_type(2)));
typedef unsigned short u16x4 __attribute__((ext_vector_type(4)));

__device__ __forceinline__ unsigned short f2bf_rne(float f) {
    unsigned int u = __builtin_bit_cast(unsigned int, f);
    u += 0x7fffu + ((u >> 16) & 1u);
    return (unsigned short)(u >> 16);
}

__device__ __forceinline__ unsigned int pack_bf2(float lo, float hi) {
    return (unsigned int)f2bf_rne(lo) | ((unsigned int)f2bf_rne(hi) << 16);
}

// ---- fused prep ----
// [0,2048): inp->bf16 tile-transposed, 4 outputs/thread:
//   inp_bf[n*64 + r*4 + t4] = inp[n*64 + t4*16 + r]
// [2048,2304): Wt ; 2304: layer-1 fold ; 2305: Wt2/Wt3 lane-major MFMA B-frags
__global__ __launch_bounds__(256) void prep_all(
    const float* __restrict__ inp, unsigned short* __restrict__ inp_bf,
    const float* __restrict__ W, unsigned short* __restrict__ Wt,
    const float* __restrict__ l1w, const float* __restrict__ l1b,
    const float* __restrict__ centers, float* __restrict__ A1,
    const float* __restrict__ l2w, const float* __restrict__ l3w,
    unsigned short* __restrict__ Wt2, unsigned short* __restrict__ Wt3)
{
    const int blk = blockIdx.x;
    const int t   = threadIdx.x;
    if (blk < 2048) {
        const int q4 = blk * 256 + t;                  // 524288 quads
        const int n  = q4 >> 4;
        const int r  = q4 & 15;
        const float* src = inp + (size_t)n * 64 + r;
        u16x4 v;
        v[0] = f2bf_rne(src[0]);
        v[1] = f2bf_rne(src[16]);
        v[2] = f2bf_rne(src[32]);
        v[3] = f2bf_rne(src[48]);
        *(u16x4*)(inp_bf + (size_t)n * 64 + r * 4) = v;
    } else if (blk < 2304) {
        const int o    = (blk - 2048) * 256 + t;       // 65536 total
        const int cout = o >> 10;
        const int kp   = o & 1023;
        const int m    = kp >> 6;
        const int cin  = kp & 63;
        Wt[o] = f2bf_rne(W[(cin * 16 + m) * 64 + cout] * (1.0f / 16.0f));
    } else if (blk == 2304) {
        if (t < 32) {
            float bb = l1b[t];
            float a0 = 0.f, a1 = 0.f, a2 = 0.f;
            for (int c = 0; c < 16; ++c) {
                const float w0 = l1w[(c     ) * 32 + t];
                const float w1 = l1w[(16 + c) * 32 + t];
                const float w2 = l1w[(32 + c) * 32 + t];
                a0 += w0; a1 += w1; a2 += w2;
                bb -= centers[c] * w0 + centers[16 + c] * w1 + centers[32 + c] * w2;
            }
            A1[0 * 32 + t] = a0; A1[1 * 32 + t] = a1; A1[2 * 32 + t] = a2; A1[3 * 32 + t] = bb;
        }
    } else {
        // Wt2[l*8+j] = l2w[k][col], k=(l>>4)*8+j, col=l&15   (B-frag, K=32)
        // Wt3[l*8+j] = k<16 ? l3w[k][col] : 0                (B-frag, K=16 zero-padded)
        for (int i = t; i < 1024; i += 256) {
            if (i < 512) {
                const int l = i >> 3, j = i & 7;
                const int k = (l >> 4) * 8 + j, col = l & 15;
                Wt2[i] = f2bf_rne(l2w[k * 16 + col]);
            } else {
                const int i3 = i - 512;
                const int l = i3 >> 3, j = i3 & 7;
                const int k = (l >> 4) * 8 + j, col = l & 15;
                Wt3[i3] = (k < 16) ? f2bf_rne(l3w[k * 16 + col]) : (unsigned short)0;
            }
        }
    }
}

__global__ __launch_bounds__(256) void ptconv_fused(
    const unsigned short* __restrict__ inp_bf, // [B,N,16,4] bf16 tile-transposed (prep)
    const float* __restrict__ points,    // [B,N,3]
    const float* __restrict__ next_pts,  // [B,N,3]
    const int*   __restrict__ indices,   // [B,N,K]
    const unsigned short* __restrict__ Wt,  // [COUT][1024] bf16 (prep)
    const unsigned short* __restrict__ Wt2, // [64][8] bf16 layer-2 B-frag
    const unsigned short* __restrict__ Wt3, // [64][8] bf16 layer-3 B-frag (zero-pad)
    const float* __restrict__ A1f,       // [4][32] folded layer-1 (prep, SoA)
    const float* __restrict__ bias,      // [COUT]
    const float* __restrict__ l2b, const float* __restrict__ l3b,
    float* __restrict__ out)             // [B,N,COUT]
{
    const int t    = threadIdx.x;
    const int lane = t & 63;
    const int w    = t >> 6;             // wave id 0..3
    const int pt0  = blockIdx.x * P;
    const int b    = pt0 >> 13;          // pt0 / NN

    // ONE 16 KB buffer; wave w owns bytes [w*4096, (w+1)*4096) until the phase-3 barrier.
    // Lifecycle (strict same-wave read -> fence -> overwrite, single may-alias array):
    //   H1 rows (64B/row, key (row&3)<<4)  ->  L2 A-reads  -> fence -> H2 overlay (32B/row)
    //   ->  L3 A-reads  -> fence ->  h3t windows overlay  ->  phase-2 reads
    //   ->  f even-half overlay.  Phase 3 reads cross-wave after barrier.
    __shared__ unsigned short s_u[P][512];        // 16 KB

    char* const wb = (char*)s_u + w * 4096;       // wave region base
    const f32x2 zero2 = {0.f, 0.f};
    const f32x4 z4 = {0.f, 0.f, 0.f, 0.f};
    const int arow = lane & 15;
    const int hi   = lane >> 4;

    // ---------------- stage 1a: h1 per thread (row = t = p*16+k), pack, H1 -> LDS ----------------
    {
        const int p = t >> 4;
        const int pt = pt0 + p;
        const int id = indices[(size_t)pt0 * KK + t];  // coalesced
        const float* pp = points + ((size_t)(b * NN + id)) * 3;
        const float* np = next_pts + (size_t)pt * 3;
        const float px = pp[0] - np[0];
        const float py = pp[1] - np[1];
        const float pz = pp[2] - np[2];
        const f32x2 px2 = {px, px}, py2 = {py, py}, pz2 = {pz, pz};

        const f32x2* A0  = (const f32x2*)(A1f);
        const f32x2* A1v = (const f32x2*)(A1f + 32);
        const f32x2* A2  = (const f32x2*)(A1f + 64);
        const f32x2* A3  = (const f32x2*)(A1f + 96);
        unsigned int pk[16];
        #pragma unroll
        for (int j = 0; j < 16; ++j) {
            f32x2 a = __builtin_elementwise_fma(pz2, A2[j], A3[j]);
            a = __builtin_elementwise_fma(py2, A1v[j], a);
            a = __builtin_elementwise_fma(px2, A0[j], a);
            a = __builtin_elementwise_max(a, zero2);
            pk[j] = pack_bf2(a[0], a[1]);          // h1 units 2j, 2j+1 (bf16)
        }
        // H1 row r'=lane, chunk c: addr = r'*64 + (c*16 ^ ((r'&3)<<4)) — key bits 4-5 only
        #pragma unroll
        for (int c = 0; c < 4; ++c) {
            const unsigned int off = (unsigned)(lane * 64)
                + ((((unsigned)c) * 16u) ^ (((unsigned)(lane & 3)) << 4));
            *(uint4*)(wb + off) = make_uint4(pk[4*c], pk[4*c+1], pk[4*c+2], pk[4*c+3]);
        }
    }
    __threadfence_block();

    // ---------------- stage 1b: layer 2 via MFMA (4 row-tiles); defer H2 overlay ----------------
    {
        const bf16x8 b2 = *(const bf16x8*)(Wt2 + lane * 8);
        const float bias2 = l2b[arow];             // D col = l&15 = h2 unit
        uint2 h2sv[4];
        #pragma unroll
        for (int T = 0; T < 4; ++T) {
            const int row = T * 16 + arow;         // local row, k-slice = hi
            const unsigned int off = (unsigned)(row * 64)
                + ((((unsigned)hi) * 16u) ^ (((unsigned)(row & 3)) << 4));
            const bf16x8 a = *(const bf16x8*)(wb + off);
            const f32x4 d = __builtin_amdgcn_mfma_f32_16x16x32_bf16(a, b2, z4, 0, 0, 0);
            h2sv[T].x = pack_bf2(fmaxf(d[0] + bias2, 0.f), fmaxf(d[1] + bias2, 0.f));
            h2sv[T].y = pack_bf2(fmaxf(d[2] + bias2, 0.f), fmaxf(d[3] + bias2, 0.f));
        }
        __threadfence_block();                     // all H1 reads retired before H2 overlay
        // D: unit=arow, local rows T*16 + hi*4 + reg.  H2: (R*32 + u*2) ^ ((R&1)<<4)
        #pragma unroll
        for (int T = 0; T < 4; ++T) {
            const unsigned short v0 = (unsigned short)(h2sv[T].x & 0xffffu);
            const unsigned short v1 = (unsigned short)(h2sv[T].x >> 16);
            const unsigned short v2 = (unsigned short)(h2sv[T].y & 0xffffu);
            const unsigned short v3 = (unsigned short)(h2sv[T].y >> 16);
            const int R0 = T * 16 + hi * 4;
            *(unsigned short*)(wb + ((unsigned)((R0+0) * 32 + arow * 2) ^ (((unsigned)((R0+0) & 1)) << 4))) = v0;
            *(unsigned short*)(wb + ((unsigned)((R0+1) * 32 + arow * 2) ^ (((unsigned)((R0+1) & 1)) << 4))) = v1;
            *(unsigned short*)(wb + ((unsigned)((R0+2) * 32 + arow * 2) ^ (((unsigned)((R0+2) & 1)) << 4))) = v2;
            *(unsigned short*)(wb + ((unsigned)((R0+3) * 32 + arow * 2) ^ (((unsigned)((R0+3) & 1)) << 4))) = v3;
        }
    }
    __threadfence_block();

    // ---------------- stage 1d/1e: layer 3 via MFMA (K zero-padded), h3t overlay ----------------
    {
        const bf16x8 b3 = *(const bf16x8*)(Wt3 + lane * 8);   // zeros for k>=16
        const float bias3 = l3b[arow];
        uint2 hsave[4];                             // defer writes until all H2 reads done
        #pragma unroll
        for (int T = 0; T < 4; ++T) {
            const int row = T * 16 + arow;
            const unsigned int off = ((unsigned)(row * 32 + hi * 16)) ^ (((unsigned)(row & 1)) << 4);
            const bf16x8 a = *(const bf16x8*)(wb + off);      // hi>=2 reads junk; b3=0 there
            const f32x4 d = __builtin_amdgcn_mfma_f32_16x16x32_bf16(a, b3, z4, 0, 0, 0);
            hsave[T].x = pack_bf2(fmaxf(d[0] + bias3, 0.f), fmaxf(d[1] + bias3, 0.f));
            hsave[T].y = pack_bf2(fmaxf(d[2] + bias3, 0.f), fmaxf(d[3] + bias3, 0.f));
        }
        __threadfence_block();                      // all H2 reads retired before h3t overlay
        // h3t: window p=w*4+T, byte m*32 + k*2 ^ ((p&3)<<5); m=arow, k = hi*4+reg.
        // The 4 u16 (k offsets 0,2,4,6) are contiguous; XOR key is bits>=5 -> one b64 store.
        #pragma unroll
        for (int T = 0; T < 4; ++T) {
            const unsigned int xw = ((unsigned)(T & 3)) << 5;
            const unsigned int base = (unsigned)(T * 1024 + arow * 32 + hi * 8);
            *(uint2*)(wb + (base ^ xw)) = make_uint2(hsave[T].x, hsave[T].y);
        }
    }
    __threadfence_block();

    // ---------------- phase 2: f = feats @ h3 via MFMA (r14 verbatim) ----------------
    uint2 holdA[2][2], holdB[2][2];
    {
        const int kg   = (hi & 1) * 8;
        const unsigned short* ibase = inp_bf + (size_t)b * NN * 64;
        const int* idxg = indices + (size_t)pt0 * KK;
        const bf16x8 vzero = {0, 0, 0, 0, 0, 0, 0, 0};
        char* fbb = (char*)s_u;

        #pragma unroll
        for (int pr = 0; pr < 2; ++pr) {
            const int pA  = w * 4 + pr * 2;
            const int pB  = pA + 1;
            const int myp = (hi < 2) ? pA : pB;

            const int4 i0 = *(const int4*)&idxg[myp * 16 + kg];
            const int4 i1 = *(const int4*)&idxg[myp * 16 + kg + 4];
            const int ids[8] = {i0.x, i0.y, i0.z, i0.w, i1.x, i1.y, i1.z, i1.w};

            u16x4 rows[8];
            #pragma unroll
            for (int jj = 0; jj < 8; ++jj)
                rows[jj] = *(const u16x4*)(ibase + (size_t)ids[jj] * 64 + arow * 4);

            const unsigned int hb = ((unsigned)(myp * 1024 + arow * 32 + kg * 2))
                                    ^ (((unsigned)(myp & 3)) << 5);
            const bf16x8 vfull = *(const bf16x8*)((const char*)s_u + hb);
            const bf16x8 bfA = (hi < 2) ? vfull : vzero;
            const bf16x8 bfB = (hi < 2) ? vzero : vfull;

            #pragma unroll
            for (int tile = 0; tile < 4; ++tile) {
                bf16x8 af;
                #pragma unroll
                for (int jj = 0; jj < 8; ++jj) af[jj] = (short)rows[jj][tile];
                const f32x4 dA = __builtin_amdgcn_mfma_f32_16x16x32_bf16(af, bfA, z4, 0, 0, 0);
                const f32x4 dB = __builtin_amdgcn_mfma_f32_16x16x32_bf16(af, bfB, z4, 0, 0, 0);
                const uint2 vA = make_uint2(pack_bf2(dA[0], dA[1]), pack_bf2(dA[2], dA[3]));
                const uint2 vB = make_uint2(pack_bf2(dB[0], dB[1]), pack_bf2(dB[2], dB[3]));
                if (tile < 2) {
                    const unsigned int baseo = (unsigned)(arow * 64 + tile * 32 + hi * 8);
                    const unsigned int offA = ((unsigned)(pA * 1024) + baseo)
                                              ^ (((unsigned)((pA & 7) ^ (arow & 7))) << 4);
                    const unsigned int offB = ((unsigned)(pB * 1024) + baseo)
                                              ^ (((unsigned)((pB & 7) ^ (arow & 7))) << 4);
                    *(uint2*)(fbb + offA) = vA;
                    *(uint2*)(fbb + offB) = vB;
                } else {
                    holdA[pr][tile - 2] = vA;
                    holdB[pr][tile - 2] = vB;
                }
            }
        }
    }
    __syncthreads();

    // ---------------- phase 3: even k-pass, swap halves, odd k-pass (r14 verbatim) ----------------
    {
        const unsigned short* wtb = Wt + (size_t)(w * 16 + arow) * 1024 + hi * 8;
        const char* fbb = (const char*)s_u;
        f32x4 acc = {0.f, 0.f, 0.f, 0.f};

        #pragma unroll
        for (int m = 0; m < 16; ++m) {   // even kk = 2m  (cin 0..31)
            const unsigned int xr = ((unsigned)((arow & 7) ^ (m & 7))) << 4;
            const bf16x8 av = *(const bf16x8*)(fbb +
                (((unsigned)(arow * 1024 + m * 64 + hi * 16)) ^ xr));
            const bf16x8 bv = *(const bf16x8*)(wtb + m * 64);
            acc = __builtin_amdgcn_mfma_f32_16x16x32_bf16(av, bv, acc, 0, 0, 0);
        }
        __syncthreads();

        {   // write odd half (cin 32..63) from hold regs
            char* fbw = (char*)s_u;
            #pragma unroll
            for (int pr = 0; pr < 2; ++pr) {
                const int pA = w * 4 + pr * 2;
                const int pB = pA + 1;
                #pragma unroll
                for (int t2 = 0; t2 < 2; ++t2) {
                    const unsigned int baseo = (unsigned)(arow * 64 + t2 * 32 + hi * 8);
                    const unsigned int offA = ((unsigned)(pA * 1024) + baseo)
                                              ^ (((unsigned)((pA & 7) ^ (arow & 7))) << 4);
                    const unsigned int offB = ((unsigned)(pB * 1024) + baseo)
                                              ^ (((unsigned)((pB & 7) ^ (arow & 7))) << 4);
                    *(uint2*)(fbw + offA) = holdA[pr][t2];
                    *(uint2*)(fbw + offB) = holdB[pr][t2];
                }
            }
        }
        __syncthreads();

        #pragma unroll
        for (int m = 0; m < 16; ++m) {   // odd kk = 2m+1  (cin 32..63)
            const unsigned int xr = ((unsigned)((arow & 7) ^ (m & 7))) << 4;
            const bf16x8 av = *(const bf16x8*)(fbb +
                (((unsigned)(arow * 1024 + m * 64 + hi * 16)) ^ xr));
            const bf16x8 bv = *(const bf16x8*)(wtb + m * 64 + 32);
            acc = __builtin_amdgcn_mfma_f32_16x16x32_bf16(av, bv, acc, 0, 0, 0);
        }

        const float bvs = bias[w * 16 + arow];
        #pragma unroll
        for (int r = 0; r < 4; ++r) {
            const int prow = hi * 4 + r;
            out[((size_t)(pt0 + prow)) * 64 + w * 16 + arow] = acc[r] + bvs;
        }
    }
}

extern "C" void kernel_launch(void* const* d_in, const int* in_sizes, int n_in,
                              void* d_out, int out_size, void* d_ws, size_t ws_size,
                              hipStream_t stream) {
    const float* inp      = (const float*)d_in[0];
    const float* points   = (const float*)d_in[1];
    const float* next_pts = (const float*)d_in[2];
    const int*   indices  = (const int*)  d_in[3];
    const float* weight   = (const float*)d_in[4];
    const float* bias     = (const float*)d_in[5];
    const float* centers  = (const float*)d_in[6];
    const float* l1w      = (const float*)d_in[7];
    const float* l1b      = (const float*)d_in[8];
    const float* l2w      = (const float*)d_in[9];
    const float* l2b      = (const float*)d_in[10];
    const float* l3w      = (const float*)d_in[11];
    const float* l3b      = (const float*)d_in[12];
    float* outp = (float*)d_out;

    unsigned short* Wt    = (unsigned short*)d_ws;                  // 128 KB @ 0
    float*          A1f   = (float*)((char*)d_ws + 131072);         // 512 B
    unsigned short* Wt2   = (unsigned short*)((char*)d_ws + 132096);// 1 KB
    unsigned short* Wt3   = (unsigned short*)((char*)d_ws + 133120);// 1 KB
    unsigned short* inpbf = (unsigned short*)((char*)d_ws + (1 << 20)); // 4 MB @ 1 MB

    prep_all<<<2306, 256, 0, stream>>>(inp, inpbf, weight, Wt,
                                       l1w, l1b, centers, A1f,
                                       l2w, l3w, Wt2, Wt3);

    const int grid = (BB * NN) / P;               // 2048 blocks
    ptconv_fused<<<grid, 256, 0, stream>>>(inpbf, points, next_pts, indices,
                                           Wt, Wt2, Wt3, A1f, bias,
                                           l2b, l3b, outp);
}